// Round 11
// baseline (423.230 us; speedup 1.0000x reference)
//
#include <hip/hip_runtime.h>
#include <math.h>

#define T_TOK 32768
#define D_DIM 128
#define K_CODE 8192
#define BM 256              // tokens per block (argmin): 4 waves x 64
#define BN 64               // codes per block (argmin)

typedef unsigned long long ull;
typedef _Float16 v8h __attribute__((ext_vector_type(8)));
typedef _Float16 v4h __attribute__((ext_vector_type(4)));
typedef float v16f __attribute__((ext_vector_type(16)));

#define SCALE 4096.0f        // 2^12: pushes f16 split residuals into normal range
#define DESCALE (1.0f / 4096.0f)
#define ACC_SCALE (-0x1p-23f)   // s' = cn - 2*dot (zn dropped: token-constant)

// Cpack layout (bytes): [cb=code/64][ (s*2+mt)*8+kc ][lane64][j8 f16]
// Zpack layout (bytes): [tb=token/32][ s ][ kc ][lane64][j8 f16]

// ---------------- prep: proj (blocks 0..2047) + prep_z (2048..3071) ---------
__global__ __launch_bounds__(256) void prep_kernel(const float* __restrict__ E,
                                                   const float* __restrict__ W,
                                                   const float* __restrict__ b,
                                                   char* __restrict__ Cpack,
                                                   float* __restrict__ cn,
                                                   const float* __restrict__ Z,
                                                   char* __restrict__ Zpack,
                                                   ull* __restrict__ packed,
                                                   int* __restrict__ counts) {
    int tid = threadIdx.x;
    int lane = tid & 63;
    if (blockIdx.x < 2048) {
        // ---- proj: codebook row -> f16 split packs + cn (1 wave / row) ----
        int r = blockIdx.x * 4 + (tid >> 6);
        int l = lane;
        const float4* E4 = (const float4*)(E + (size_t)r * D_DIM);
        const float4* WA = (const float4*)(W + (size_t)l * D_DIM);
        const float4* WB = (const float4*)(W + (size_t)(l + 64) * D_DIM);

        float4 aA = make_float4(0.f, 0.f, 0.f, 0.f);
        float4 aB = make_float4(0.f, 0.f, 0.f, 0.f);
#pragma unroll
        for (int dd = 0; dd < 32; ++dd) {
            float4 e = E4[dd];
            float4 wa = WA[dd], wb = WB[dd];
            aA.x = fmaf(e.x, wa.x, aA.x);
            aA.y = fmaf(e.y, wa.y, aA.y);
            aA.z = fmaf(e.z, wa.z, aA.z);
            aA.w = fmaf(e.w, wa.w, aA.w);
            aB.x = fmaf(e.x, wb.x, aB.x);
            aB.y = fmaf(e.y, wb.y, aB.y);
            aB.z = fmaf(e.z, wb.z, aB.z);
            aB.w = fmaf(e.w, wb.w, aB.w);
        }
        float vA = ((aA.x + aA.y) + (aA.z + aA.w)) + b[l];
        float vB = ((aB.x + aB.y) + (aB.z + aB.w)) + b[l + 64];

        char* cp = Cpack + (size_t)(r >> 6) * 32768;
        int mt = (r >> 5) & 1, rs = r & 31;
        {   // d = l
            int kc = l >> 4, hf = (l >> 3) & 1, j = l & 7;
            float f = vA * SCALE;
            _Float16 h = (_Float16)f;
            _Float16 m = (_Float16)(f - (float)h);
            size_t off = (size_t)((mt * 8 + kc) * 1024 + (hf * 32 + rs) * 16 + j * 2);
            *(_Float16*)(cp + off) = h;
            *(_Float16*)(cp + off + 16384) = m;
        }
        {   // d = l + 64
            int d = l + 64;
            int kc = d >> 4, hf = (d >> 3) & 1, j = d & 7;
            float f = vB * SCALE;
            _Float16 h = (_Float16)f;
            _Float16 m = (_Float16)(f - (float)h);
            size_t off = (size_t)((mt * 8 + kc) * 1024 + (hf * 32 + rs) * 16 + j * 2);
            *(_Float16*)(cp + off) = h;
            *(_Float16*)(cp + off + 16384) = m;
        }

        float s = vA * vA + vB * vB;
#pragma unroll
        for (int off = 32; off > 0; off >>= 1) s += __shfl_down(s, off, 64);
        if (l == 0) cn[r] = s;
    } else {
        // ---- prep_z: z -> f16 split packs + fused inits ----
        int tb = blockIdx.x - 2048;   // 32-token group
        int w = tid >> 6;

        int g = tb * 256 + tid;
        if (g < T_TOK) packed[g] = ~0ull;
        if (g < K_CODE) counts[g] = 0;

        char* zp = Zpack + (size_t)tb * 16384;
#pragma unroll
        for (int kq = 0; kq < 2; ++kq) {
            int kc = 2 * w + kq;
            const float* src = Z + (size_t)(tb * 32 + (lane & 31)) * D_DIM
                                 + kc * 16 + (lane >> 5) * 8;
            float4 a = *(const float4*)(src);
            float4 c = *(const float4*)(src + 4);
            float vals[8] = {a.x, a.y, a.z, a.w, c.x, c.y, c.z, c.w};
            v8h h, m;
#pragma unroll
            for (int j = 0; j < 8; ++j) {
                float f = vals[j] * SCALE;
                _Float16 hh = (_Float16)f;
                h[j] = hh;
                m[j] = (_Float16)(f - (float)hh);
            }
            *(v8h*)(zp + (size_t)(kc * 1024 + lane * 16)) = h;
            *(v8h*)(zp + (size_t)(8192 + kc * 1024 + lane * 16)) = m;
        }
    }
}

// ---------------- MFMA argmin: barrier-free, LDS-free (phase-skeleton probe)
// R19 post-mortem chain: SIX nulls (occupancy x2, B-prefetch 2->3 deep, A
// LDS double-buffer, block 256/512, setprio, staging style) all pin argmin
// at 206-208us / 47-51% MfmaUtil = 7760 cyc/block vs 3100-cyc matrix floor.
// Intra-K-loop waits are exonerated (R8/R10). The one thing every variant
// shared: the block phase skeleton (stage -> vmcnt(0)+barrier -> K-loop ->
// epilogue -> retire) with co-resident blocks starting/retiring in lockstep
// -> phases convoy, matrix drains each generation. R11 removes the skeleton:
// NO LDS, NO barrier -- A fragments read straight from L2 (Cpack chunk is
// hot/L2-resident; SAME linear offsets as the staged layout = identical
// bytes), cn read in epilogue. Pure prefetched-load+MFMA stream per wave;
// blocks desynchronize freely. Cost: A traffic x4 from L2 (+2.1GB, partially
// L1-absorbed: 4 waves/block share bytes). If this REGRESSES, the staged
// variants were at an effective-L2 ceiling and 207us is a memory roofline.
// Regs: A 2-slot (32) + pb 3-slot (48) + acc 64 + addr ~20 = ~164 <= 170 at
// (256,3). MFMA order, epilogue arithmetic, tie-breaks, atomics R10-exact.
__global__ __launch_bounds__(256, 3) void argmin_kernel(const char* __restrict__ Zpack,
                                                        const char* __restrict__ Cpack,
                                                        const float* __restrict__ cn,
                                                        ull* __restrict__ packed) {
    int tid = threadIdx.x;
    int lane = tid & 63;
    int w = tid >> 6;                  // 0..3
    int half_id = lane >> 5;

    // XCD swizzle (R5-identical): window in HIGH bits of q -> co-resident
    // blocks share one window (L2-hot Zpack); Cpack cycles L2-resident.
    int bid = blockIdx.x;
    int xcd = bid & 7;
    int q = bid >> 3;
    int cb = q & 127;                  // code block (64 codes)
    int win = xcd + 8 * (q >> 7);      // token window (256 tokens)
    int nb = cb * BN;
    int mb = win * BM;

    int tbw = (mb >> 5) + 2 * w;       // wave w owns token groups 2w, 2w+1
    const char* zb0 = Zpack + (size_t)tbw * 16384 + lane * 16;
    const char* abg = Cpack + (size_t)cb * 32768 + lane * 16;   // A from L2

    // 3-slot B prefetch: pb[frag = n*2 + split][slot = kc%3]
    v8h pb[4][3];
#pragma unroll
    for (int n = 0; n < 2; ++n) {
        pb[2 * n + 0][0] = *(const v8h*)(zb0 + n * 16384);
        pb[2 * n + 1][0] = *(const v8h*)(zb0 + n * 16384 + 8192);
        pb[2 * n + 0][1] = *(const v8h*)(zb0 + n * 16384 + 1024);
        pb[2 * n + 1][1] = *(const v8h*)(zb0 + n * 16384 + 8192 + 1024);
    }

    // A double-buffer from global: Af[kc&1][frag], prologue loads kc=0
    v8h Af[2][4];
#pragma unroll
    for (int f = 0; f < 4; ++f)
        Af[0][f] = *(const v8h*)(abg + (f * 8 + 0) * 1024);

    v16f acc[2][2];               // [mt codes][n token-groups]
#pragma unroll
    for (int mt = 0; mt < 2; ++mt)
#pragma unroll
        for (int n = 0; n < 2; ++n) acc[mt][n] = (v16f)0.f;

#pragma unroll
    for (int kc = 0; kc < 8; ++kc) {
        int curb = kc % 3;
        int cura = kc & 1;

        // issue kc+1's A loads FIRST (consumed after 12 MFMAs)
        if (kc < 7) {
#pragma unroll
            for (int f = 0; f < 4; ++f)
                Af[cura ^ 1][f] = *(const v8h*)(abg + (f * 8 + kc + 1) * 1024);
        }

        // deep B refill: slot (kc+2)%3 consumed at kc-1; data used at kc+2
        if (kc < 6) {
            int slot = (kc + 2) % 3;
#pragma unroll
            for (int n = 0; n < 2; ++n) {
                pb[2 * n + 0][slot] = *(const v8h*)(zb0 + n * 16384 + (kc + 2) * 1024);
                pb[2 * n + 1][slot] = *(const v8h*)(zb0 + n * 16384 + 8192 + (kc + 2) * 1024);
            }
        }

        __builtin_amdgcn_s_setprio(1);
        // pass h*h
#pragma unroll
        for (int n = 0; n < 2; ++n)
            acc[0][n] = __builtin_amdgcn_mfma_f32_32x32x16_f16(Af[cura][0], pb[2 * n][curb], acc[0][n], 0, 0, 0);
#pragma unroll
        for (int n = 0; n < 2; ++n)
            acc[1][n] = __builtin_amdgcn_mfma_f32_32x32x16_f16(Af[cura][1], pb[2 * n][curb], acc[1][n], 0, 0, 0);
        // pass h*m
#pragma unroll
        for (int n = 0; n < 2; ++n)
            acc[0][n] = __builtin_amdgcn_mfma_f32_32x32x16_f16(Af[cura][0], pb[2 * n + 1][curb], acc[0][n], 0, 0, 0);
#pragma unroll
        for (int n = 0; n < 2; ++n)
            acc[1][n] = __builtin_amdgcn_mfma_f32_32x32x16_f16(Af[cura][1], pb[2 * n + 1][curb], acc[1][n], 0, 0, 0);
        // pass m*h
#pragma unroll
        for (int n = 0; n < 2; ++n)
            acc[0][n] = __builtin_amdgcn_mfma_f32_32x32x16_f16(Af[cura][2], pb[2 * n][curb], acc[0][n], 0, 0, 0);
#pragma unroll
        for (int n = 0; n < 2; ++n)
            acc[1][n] = __builtin_amdgcn_mfma_f32_32x32x16_f16(Af[cura][3], pb[2 * n][curb], acc[1][n], 0, 0, 0);
        __builtin_amdgcn_s_setprio(0);
    }

    // ---- epilogue: in-lane argmin per token group (zn-free: s' = cn - 2dot,
    // token-constant zn cancels in every comparison). cn direct from global
    // (256 B region, L1/L2-hot: every window's blocks re-read it).
    float best[2];
    int bi[2];
#pragma unroll
    for (int n = 0; n < 2; ++n) { best[n] = 3.4e38f; bi[n] = nb; }

#pragma unroll
    for (int mt = 0; mt < 2; ++mt) {
        float cnreg[16];
#pragma unroll
        for (int reg = 0; reg < 16; ++reg) {
            int mrow = 32 * mt + (reg & 3) + 8 * (reg >> 2) + 4 * half_id;
            cnreg[reg] = cn[nb + mrow];
        }
#pragma unroll
        for (int n = 0; n < 2; ++n) {
#pragma unroll
            for (int reg = 0; reg < 16; ++reg) {
                // ascending code order within half -> strict < keeps first-min
                int mrow = 32 * mt + (reg & 3) + 8 * (reg >> 2) + 4 * half_id;
                int code = nb + mrow;
                float s = fmaf(acc[mt][n][reg], ACC_SCALE, cnreg[reg]);
                if (s < best[n]) { best[n] = s; bi[n] = code; }
            }
        }
    }

    // cross-half combine + XCD-local packed atomicMin
#pragma unroll
    for (int n = 0; n < 2; ++n) {
        float ob = __shfl_xor(best[n], 32, 64);
        int oi = __shfl_xor(bi[n], 32, 64);
        if (ob < best[n] || (ob == best[n] && oi < bi[n])) { best[n] = ob; bi[n] = oi; }
        if ((n & 1) == half_id) {
            int tok = mb + w * 64 + n * 32 + (lane & 31);
            // monotone total-order encode of f32 (s' may be negative):
            // >=0: u^0x80000000 ; <0: u^0xFFFFFFFF. Equal s' -> equal key ->
            // min picks smaller code in low bits (first-min ties preserved).
            unsigned ub = __float_as_uint(best[n]);
            unsigned key = ub ^ ((unsigned)(((int)ub) >> 31) | 0x80000000u);
            ull pk = ((ull)key << 32) | (unsigned)bi[n];
            atomicMin(&packed[tok], pk);
        }
    }
}

// ---------------- zq: unpack winner, reconstruct code row, out + counts + loss
__global__ __launch_bounds__(256) void zq_kernel(const float* __restrict__ Z,
                                                 const char* __restrict__ Cpack,
                                                 const ull* __restrict__ packed,
                                                 float* __restrict__ out,
                                                 int* __restrict__ counts,
                                                 float* __restrict__ lpart) {
    int gid = blockIdx.x * 256 + threadIdx.x;   // over T*D/4 float4s
    int t = gid >> 5;                           // 32 float4 per token
    int d4 = gid & 31;
    int idx = (int)(packed[t] & 0xFFFFFFFFull);
    if (d4 == 0) atomicAdd(&counts[idx], 1);

    // reconstruct c[d0..d0+3] = (ch + cm) * 2^-12 (exact sum: spans < 24 bits)
    int d0 = 4 * d4;
    int kc = d0 >> 4, hf = (d0 >> 3) & 1, j0 = d0 & 7;
    const char* cp = Cpack + (size_t)(idx >> 6) * 32768
                   + (size_t)((((idx >> 5) & 1) * 8 + kc) * 1024
                              + (hf * 32 + (idx & 31)) * 16 + j0 * 2);
    v4h h = *(const v4h*)(cp);
    v4h m = *(const v4h*)(cp + 16384);
    float4 cv;
    cv.x = ((float)h[0] + (float)m[0]) * DESCALE;
    cv.y = ((float)h[1] + (float)m[1]) * DESCALE;
    cv.z = ((float)h[2] + (float)m[2]) * DESCALE;
    cv.w = ((float)h[3] + (float)m[3]) * DESCALE;

    float4 zv = ((const float4*)Z)[gid];
    float dx = cv.x - zv.x, dy = cv.y - zv.y, dz = cv.z - zv.z, dw = cv.w - zv.w;
    float4 o;
    o.x = zv.x + dx;    // z + (z_q - z): match reference elementwise rounding
    o.y = zv.y + dy;
    o.z = zv.z + dz;
    o.w = zv.w + dw;
    ((float4*)out)[gid] = o;

    float ls = dx * dx + dy * dy + dz * dz + dw * dw;
#pragma unroll
    for (int off = 32; off > 0; off >>= 1) ls += __shfl_down(ls, off, 64);
    __shared__ float red[4];
    int lane = threadIdx.x & 63, w = threadIdx.x >> 6;
    if (lane == 0) red[w] = ls;
    __syncthreads();
    // per-block partial store: no same-address atomic serialization
    if (threadIdx.x == 0) lpart[blockIdx.x] = (red[0] + red[1]) + (red[2] + red[3]);
}

// ---------------- scalars: commit_loss (from partials), perplexity ----------
__global__ __launch_bounds__(256) void scalars_kernel(const int* __restrict__ counts,
                                                      const float* __restrict__ lpart,
                                                      float* __restrict__ out) {
    float s = 0.f;
    for (int i = threadIdx.x; i < K_CODE; i += 256) {
        float e = (float)counts[i] * (1.0f / (float)T_TOK);
        s += e * logf(e + 1e-8f);
    }
    float ls = 0.f;
    for (int i = threadIdx.x; i < 4096; i += 256) ls += lpart[i];
#pragma unroll
    for (int off = 32; off > 0; off >>= 1) {
        s += __shfl_down(s, off, 64);
        ls += __shfl_down(ls, off, 64);
    }
    __shared__ float red[8];
    int lane = threadIdx.x & 63, w = threadIdx.x >> 6;
    if (lane == 0) { red[w] = s; red[4 + w] = ls; }
    __syncthreads();
    if (threadIdx.x == 0) {
        float ssum = (red[0] + red[1]) + (red[2] + red[3]);
        float lsum = (red[4] + red[5]) + (red[6] + red[7]);
        out[(size_t)T_TOK * D_DIM + 0] = 1.25f * lsum / (float)((size_t)T_TOK * D_DIM);
        out[(size_t)T_TOK * D_DIM + 1] = expf(-ssum);
    }
}

extern "C" void kernel_launch(void* const* d_in, const int* in_sizes, int n_in,
                              void* d_out, int out_size, void* d_ws, size_t ws_size,
                              hipStream_t stream) {
    const float* z   = (const float*)d_in[0];   // [8,4096,128]
    const float* emb = (const float*)d_in[1];   // [8192,128]
    const float* pw  = (const float*)d_in[2];   // [128,128]
    const float* pb  = (const float*)d_in[3];   // [128]
    float* out = (float*)d_out;

    // Zpack (f16 split fragments, 16.78 MB) lives in d_out: dead scratch until
    // zq_kernel overwrites d_out with the final z_q_st.
    char* Zpack = (char*)d_out;

    char* ws = (char*)d_ws;
    // layout (bytes):
    //   Cpack:  0        .. 4194304   (128 cb x 32768)
    //   cn:     4194304  .. 4227072   (8192 f32)
    //   lpart:  4227072  .. 4243456   (4096 f32)
    //   packed: 4358144  .. 4620288   (32768 u64)
    //   counts: 4620288  .. 4653056   (8192 i32)
    char*  Cpack  = ws + 0;
    float* cn     = (float*)(ws + 4194304);
    float* lpart  = (float*)(ws + 4227072);
    ull*   packed = (ull*)  (ws + 4358144);
    int*   counts = (int*)  (ws + 4620288);

    prep_kernel<<<3072, 256, 0, stream>>>(emb, pw, pb, Cpack, cn, z, Zpack, packed, counts);
    argmin_kernel<<<(K_CODE / BN) * (T_TOK / BM), 256, 0, stream>>>(Zpack, Cpack, cn, packed);
    zq_kernel<<<(T_TOK * D_DIM / 4) / 256, 256, 0, stream>>>(z, Cpack, packed, out, counts, lpart);
    scalars_kernel<<<1, 256, 0, stream>>>(counts, lpart, out);
}

// Round 12
// 382.174 us; speedup vs baseline: 1.1074x; 1.1074x over previous
//
#include <hip/hip_runtime.h>
#include <math.h>

#define T_TOK 32768
#define D_DIM 128
#define K_CODE 8192
#define BM 256              // tokens per block (argmin): 4 waves x 64
#define BN 64               // codes per block (argmin)

typedef unsigned long long ull;
typedef _Float16 v8h __attribute__((ext_vector_type(8)));
typedef _Float16 v4h __attribute__((ext_vector_type(4)));
typedef float v16f __attribute__((ext_vector_type(16)));

#define SCALE 4096.0f        // 2^12: pushes f16 split residuals into normal range
#define DESCALE (1.0f / 4096.0f)
#define ACC_SCALE (-0x1p-23f)   // s' = cn - 2*dot (zn dropped: token-constant)

// Cpack layout (bytes): [cb=code/64][ (s*2+mt)*8+kc ][lane64][j8 f16]
// Zpack layout (bytes): [tb=token/32][ s ][ kc ][lane64][j8 f16]

// ---------------- prep: proj (blocks 0..2047) + prep_z (2048..3071) ---------
__global__ __launch_bounds__(256) void prep_kernel(const float* __restrict__ E,
                                                   const float* __restrict__ W,
                                                   const float* __restrict__ b,
                                                   char* __restrict__ Cpack,
                                                   float* __restrict__ cn,
                                                   const float* __restrict__ Z,
                                                   char* __restrict__ Zpack,
                                                   ull* __restrict__ packed,
                                                   int* __restrict__ counts) {
    int tid = threadIdx.x;
    int lane = tid & 63;
    if (blockIdx.x < 2048) {
        // ---- proj: codebook row -> f16 split packs + cn (1 wave / row) ----
        int r = blockIdx.x * 4 + (tid >> 6);
        int l = lane;
        const float4* E4 = (const float4*)(E + (size_t)r * D_DIM);
        const float4* WA = (const float4*)(W + (size_t)l * D_DIM);
        const float4* WB = (const float4*)(W + (size_t)(l + 64) * D_DIM);

        float4 aA = make_float4(0.f, 0.f, 0.f, 0.f);
        float4 aB = make_float4(0.f, 0.f, 0.f, 0.f);
#pragma unroll
        for (int dd = 0; dd < 32; ++dd) {
            float4 e = E4[dd];
            float4 wa = WA[dd], wb = WB[dd];
            aA.x = fmaf(e.x, wa.x, aA.x);
            aA.y = fmaf(e.y, wa.y, aA.y);
            aA.z = fmaf(e.z, wa.z, aA.z);
            aA.w = fmaf(e.w, wa.w, aA.w);
            aB.x = fmaf(e.x, wb.x, aB.x);
            aB.y = fmaf(e.y, wb.y, aB.y);
            aB.z = fmaf(e.z, wb.z, aB.z);
            aB.w = fmaf(e.w, wb.w, aB.w);
        }
        float vA = ((aA.x + aA.y) + (aA.z + aA.w)) + b[l];
        float vB = ((aB.x + aB.y) + (aB.z + aB.w)) + b[l + 64];

        char* cp = Cpack + (size_t)(r >> 6) * 32768;
        int mt = (r >> 5) & 1, rs = r & 31;
        {   // d = l
            int kc = l >> 4, hf = (l >> 3) & 1, j = l & 7;
            float f = vA * SCALE;
            _Float16 h = (_Float16)f;
            _Float16 m = (_Float16)(f - (float)h);
            size_t off = (size_t)((mt * 8 + kc) * 1024 + (hf * 32 + rs) * 16 + j * 2);
            *(_Float16*)(cp + off) = h;
            *(_Float16*)(cp + off + 16384) = m;
        }
        {   // d = l + 64
            int d = l + 64;
            int kc = d >> 4, hf = (d >> 3) & 1, j = d & 7;
            float f = vB * SCALE;
            _Float16 h = (_Float16)f;
            _Float16 m = (_Float16)(f - (float)h);
            size_t off = (size_t)((mt * 8 + kc) * 1024 + (hf * 32 + rs) * 16 + j * 2);
            *(_Float16*)(cp + off) = h;
            *(_Float16*)(cp + off + 16384) = m;
        }

        float s = vA * vA + vB * vB;
#pragma unroll
        for (int off = 32; off > 0; off >>= 1) s += __shfl_down(s, off, 64);
        if (l == 0) cn[r] = s;
    } else {
        // ---- prep_z: z -> f16 split packs + fused inits ----
        int tb = blockIdx.x - 2048;   // 32-token group
        int w = tid >> 6;

        int g = tb * 256 + tid;
        if (g < T_TOK) packed[g] = ~0ull;
        if (g < K_CODE) counts[g] = 0;

        char* zp = Zpack + (size_t)tb * 16384;
#pragma unroll
        for (int kq = 0; kq < 2; ++kq) {
            int kc = 2 * w + kq;
            const float* src = Z + (size_t)(tb * 32 + (lane & 31)) * D_DIM
                                 + kc * 16 + (lane >> 5) * 8;
            float4 a = *(const float4*)(src);
            float4 c = *(const float4*)(src + 4);
            float vals[8] = {a.x, a.y, a.z, a.w, c.x, c.y, c.z, c.w};
            v8h h, m;
#pragma unroll
            for (int j = 0; j < 8; ++j) {
                float f = vals[j] * SCALE;
                _Float16 hh = (_Float16)f;
                h[j] = hh;
                m[j] = (_Float16)(f - (float)hh);
            }
            *(v8h*)(zp + (size_t)(kc * 1024 + lane * 16)) = h;
            *(v8h*)(zp + (size_t)(8192 + kc * 1024 + lane * 16)) = m;
        }
    }
}

// ---------------- MFMA argmin: R10 base + packed-key tree epilogue ----------
// R20 consolidation: R11 (no-LDS probe) regressed (FETCH 128->290MB, +68us
// L2 pipe) -> LDS staging is load-bearing; the staged config is the memory-
// subsystem equilibrium. Seven schedule probes (occupancy, B-depth, A-dbuf,
// block shape, barriers, persistence x2) all null/regress around 207us.
// The one untried theory-backed lever: the epilogue's 32-deep SERIAL
// compare-select chain (~800 dependent cyc/wave, phase-aligned across waves).
// Replace with packed-u64-key min (encode(s)<<32|code -- the SAME key the
// atomic uses): 4 independent chains of 8 + 2-level combine. Associative &
// commutative with distinct codes => (min s, then min code) == serial
// first-min EXACTLY; cross-half combine becomes shfl + one u64 min.
// K-loop, staging, swizzle, atomics byte-identical to R10.
__global__ __launch_bounds__(256, 3) void argmin_kernel(const char* __restrict__ Zpack,
                                                        const char* __restrict__ Cpack,
                                                        const float* __restrict__ cn,
                                                        ull* __restrict__ packed) {
    __shared__ __align__(16) char lds[33024];   // 32768 A-pack + 256 cn

    int tid = threadIdx.x;
    int lane = tid & 63;
    int w = tid >> 6;                  // 0..3
    int half_id = lane >> 5;

    // XCD swizzle: window in HIGH bits of q -> co-resident blocks share one
    // window (L2-hot Zpack); Cpack cycles L2-resident.
    int bid = blockIdx.x;
    int xcd = bid & 7;
    int q = bid >> 3;
    int cb = q & 127;                  // code block (64 codes)
    int win = xcd + 8 * (q >> 7);      // token window (256 tokens)
    int nb = cb * BN;
    int mb = win * BM;

    // ---- one-time stage: A-pack via async global_load_lds (16B, linear) ----
    {
        const char* src = Cpack + (size_t)cb * 32768;
#pragma unroll
        for (int it = 0; it < 8; ++it) {
            int off = it * 4096 + tid * 16;
            __builtin_amdgcn_global_load_lds(
                (const __attribute__((address_space(1))) void*)(src + off),
                (__attribute__((address_space(3))) void*)(lds + off),
                16, 0, 0);
        }
        if (tid < 64) ((float*)(lds + 32768))[tid] = cn[nb + tid];
    }

    int tbw = (mb >> 5) + 2 * w;       // wave w owns token groups 2w, 2w+1
    const char* zb0 = Zpack + (size_t)tbw * 16384 + lane * 16;

    // 3-slot register prefetch: pb[frag = n*2 + split][slot = kc%3]
    v8h pb[4][3];
#pragma unroll
    for (int n = 0; n < 2; ++n) {
        pb[2 * n + 0][0] = *(const v8h*)(zb0 + n * 16384);
        pb[2 * n + 1][0] = *(const v8h*)(zb0 + n * 16384 + 8192);
        pb[2 * n + 0][1] = *(const v8h*)(zb0 + n * 16384 + 1024);
        pb[2 * n + 1][1] = *(const v8h*)(zb0 + n * 16384 + 8192 + 1024);
    }

    __syncthreads();   // drains staging; LDS read-only after this

    const char* ab = lds + lane * 16;
    const float* cn_s = (const float*)(lds + 32768);

    v16f acc[2][2];               // [mt codes][n token-groups]
#pragma unroll
    for (int mt = 0; mt < 2; ++mt)
#pragma unroll
        for (int n = 0; n < 2; ++n) acc[mt][n] = (v16f)0.f;

    // A double-buffer: Af[kc&1][frag] -- prologue loads kc=0 (post-barrier)
    v8h Af[2][4];
#pragma unroll
    for (int f = 0; f < 4; ++f)
        Af[0][f] = *(const v8h*)(ab + (f * 8 + 0) * 1024);

#pragma unroll
    for (int kc = 0; kc < 8; ++kc) {
        int curb = kc % 3;
        int cura = kc & 1;

        // issue kc+1's A ds_reads FIRST (consumed after 12 MFMAs)
        if (kc < 7) {
#pragma unroll
            for (int f = 0; f < 4; ++f)
                Af[cura ^ 1][f] = *(const v8h*)(ab + (f * 8 + kc + 1) * 1024);
        }

        // deep B refill: slot (kc+2)%3 consumed at kc-1; data used at kc+2
        if (kc < 6) {
            int slot = (kc + 2) % 3;
#pragma unroll
            for (int n = 0; n < 2; ++n) {
                pb[2 * n + 0][slot] = *(const v8h*)(zb0 + n * 16384 + (kc + 2) * 1024);
                pb[2 * n + 1][slot] = *(const v8h*)(zb0 + n * 16384 + 8192 + (kc + 2) * 1024);
            }
        }

        __builtin_amdgcn_s_setprio(1);
        // pass h*h
#pragma unroll
        for (int n = 0; n < 2; ++n)
            acc[0][n] = __builtin_amdgcn_mfma_f32_32x32x16_f16(Af[cura][0], pb[2 * n][curb], acc[0][n], 0, 0, 0);
#pragma unroll
        for (int n = 0; n < 2; ++n)
            acc[1][n] = __builtin_amdgcn_mfma_f32_32x32x16_f16(Af[cura][1], pb[2 * n][curb], acc[1][n], 0, 0, 0);
        // pass h*m
#pragma unroll
        for (int n = 0; n < 2; ++n)
            acc[0][n] = __builtin_amdgcn_mfma_f32_32x32x16_f16(Af[cura][0], pb[2 * n + 1][curb], acc[0][n], 0, 0, 0);
#pragma unroll
        for (int n = 0; n < 2; ++n)
            acc[1][n] = __builtin_amdgcn_mfma_f32_32x32x16_f16(Af[cura][1], pb[2 * n + 1][curb], acc[1][n], 0, 0, 0);
        // pass m*h
#pragma unroll
        for (int n = 0; n < 2; ++n)
            acc[0][n] = __builtin_amdgcn_mfma_f32_32x32x16_f16(Af[cura][2], pb[2 * n][curb], acc[0][n], 0, 0, 0);
#pragma unroll
        for (int n = 0; n < 2; ++n)
            acc[1][n] = __builtin_amdgcn_mfma_f32_32x32x16_f16(Af[cura][3], pb[2 * n][curb], acc[1][n], 0, 0, 0);
        __builtin_amdgcn_s_setprio(0);
    }

    // ---- epilogue: packed-key argmin (exact first-min semantics) ----
    // key = monotone(s')<<32 | code. Equal s' -> equal hi word -> u64 min
    // falls through to the smaller code. Associative/commutative with
    // distinct codes => any reduction tree == serial first-min. 4 chains
    // of 8 (independent, ILP) + 2-level combine replaces the 32-deep
    // dependent compare-select chain.
#pragma unroll
    for (int n = 0; n < 2; ++n) {
        ull ck[4];
#pragma unroll
        for (int c = 0; c < 4; ++c) ck[c] = ~0ull;

#pragma unroll
        for (int mt = 0; mt < 2; ++mt) {
#pragma unroll
            for (int reg = 0; reg < 16; ++reg) {
                int mrow = 32 * mt + (reg & 3) + 8 * (reg >> 2) + 4 * half_id;
                int code = nb + mrow;
                float s = fmaf(acc[mt][n][reg], ACC_SCALE, cn_s[mrow]);
                // monotone total-order encode of f32 (s' may be negative):
                // >=0: u^0x80000000 ; <0: u^0xFFFFFFFF
                unsigned ub = __float_as_uint(s);
                unsigned key = ub ^ ((unsigned)(((int)ub) >> 31) | 0x80000000u);
                ull pk = ((ull)key << 32) | (unsigned)code;
                int c = reg & 3;               // 4 independent chains
                ck[c] = (pk < ck[c]) ? pk : ck[c];
            }
        }
        ull k01 = (ck[0] < ck[1]) ? ck[0] : ck[1];
        ull k23 = (ck[2] < ck[3]) ? ck[2] : ck[3];
        ull bk = (k01 < k23) ? k01 : k23;

        // cross-half combine: one shfl + one u64 min (same key space)
        ull ok = __shfl_xor((long long)bk, 32, 64);
        bk = (ok < bk) ? ok : bk;

        if ((n & 1) == half_id) {
            int tok = mb + w * 64 + n * 32 + (lane & 31);
            atomicMin(&packed[tok], bk);
        }
    }
}

// ---------------- zq: unpack winner, reconstruct code row, out + counts + loss
__global__ __launch_bounds__(256) void zq_kernel(const float* __restrict__ Z,
                                                 const char* __restrict__ Cpack,
                                                 const ull* __restrict__ packed,
                                                 float* __restrict__ out,
                                                 int* __restrict__ counts,
                                                 float* __restrict__ lpart) {
    int gid = blockIdx.x * 256 + threadIdx.x;   // over T*D/4 float4s
    int t = gid >> 5;                           // 32 float4 per token
    int d4 = gid & 31;
    int idx = (int)(packed[t] & 0xFFFFFFFFull);
    if (d4 == 0) atomicAdd(&counts[idx], 1);

    // reconstruct c[d0..d0+3] = (ch + cm) * 2^-12 (exact sum: spans < 24 bits)
    int d0 = 4 * d4;
    int kc = d0 >> 4, hf = (d0 >> 3) & 1, j0 = d0 & 7;
    const char* cp = Cpack + (size_t)(idx >> 6) * 32768
                   + (size_t)((((idx >> 5) & 1) * 8 + kc) * 1024
                              + (hf * 32 + (idx & 31)) * 16 + j0 * 2);
    v4h h = *(const v4h*)(cp);
    v4h m = *(const v4h*)(cp + 16384);
    float4 cv;
    cv.x = ((float)h[0] + (float)m[0]) * DESCALE;
    cv.y = ((float)h[1] + (float)m[1]) * DESCALE;
    cv.z = ((float)h[2] + (float)m[2]) * DESCALE;
    cv.w = ((float)h[3] + (float)m[3]) * DESCALE;

    float4 zv = ((const float4*)Z)[gid];
    float dx = cv.x - zv.x, dy = cv.y - zv.y, dz = cv.z - zv.z, dw = cv.w - zv.w;
    float4 o;
    o.x = zv.x + dx;    // z + (z_q - z): match reference elementwise rounding
    o.y = zv.y + dy;
    o.z = zv.z + dz;
    o.w = zv.w + dw;
    ((float4*)out)[gid] = o;

    float ls = dx * dx + dy * dy + dz * dz + dw * dw;
#pragma unroll
    for (int off = 32; off > 0; off >>= 1) ls += __shfl_down(ls, off, 64);
    __shared__ float red[4];
    int lane = threadIdx.x & 63, w = threadIdx.x >> 6;
    if (lane == 0) red[w] = ls;
    __syncthreads();
    // per-block partial store: no same-address atomic serialization
    if (threadIdx.x == 0) lpart[blockIdx.x] = (red[0] + red[1]) + (red[2] + red[3]);
}

// ---------------- scalars: commit_loss (from partials), perplexity ----------
__global__ __launch_bounds__(256) void scalars_kernel(const int* __restrict__ counts,
                                                      const float* __restrict__ lpart,
                                                      float* __restrict__ out) {
    float s = 0.f;
    for (int i = threadIdx.x; i < K_CODE; i += 256) {
        float e = (float)counts[i] * (1.0f / (float)T_TOK);
        s += e * logf(e + 1e-8f);
    }
    float ls = 0.f;
    for (int i = threadIdx.x; i < 4096; i += 256) ls += lpart[i];
#pragma unroll
    for (int off = 32; off > 0; off >>= 1) {
        s += __shfl_down(s, off, 64);
        ls += __shfl_down(ls, off, 64);
    }
    __shared__ float red[8];
    int lane = threadIdx.x & 63, w = threadIdx.x >> 6;
    if (lane == 0) { red[w] = s; red[4 + w] = ls; }
    __syncthreads();
    if (threadIdx.x == 0) {
        float ssum = (red[0] + red[1]) + (red[2] + red[3]);
        float lsum = (red[4] + red[5]) + (red[6] + red[7]);
        out[(size_t)T_TOK * D_DIM + 0] = 1.25f * lsum / (float)((size_t)T_TOK * D_DIM);
        out[(size_t)T_TOK * D_DIM + 1] = expf(-ssum);
    }
}

extern "C" void kernel_launch(void* const* d_in, const int* in_sizes, int n_in,
                              void* d_out, int out_size, void* d_ws, size_t ws_size,
                              hipStream_t stream) {
    const float* z   = (const float*)d_in[0];   // [8,4096,128]
    const float* emb = (const float*)d_in[1];   // [8192,128]
    const float* pw  = (const float*)d_in[2];   // [128,128]
    const float* pb  = (const float*)d_in[3];   // [128]
    float* out = (float*)d_out;

    // Zpack (f16 split fragments, 16.78 MB) lives in d_out: dead scratch until
    // zq_kernel overwrites d_out with the final z_q_st.
    char* Zpack = (char*)d_out;

    char* ws = (char*)d_ws;
    // layout (bytes):
    //   Cpack:  0        .. 4194304   (128 cb x 32768)
    //   cn:     4194304  .. 4227072   (8192 f32)
    //   lpart:  4227072  .. 4243456   (4096 f32)
    //   packed: 4358144  .. 4620288   (32768 u64)
    //   counts: 4620288  .. 4653056   (8192 i32)
    char*  Cpack  = ws + 0;
    float* cn     = (float*)(ws + 4194304);
    float* lpart  = (float*)(ws + 4227072);
    ull*   packed = (ull*)  (ws + 4358144);
    int*   counts = (int*)  (ws + 4620288);

    prep_kernel<<<3072, 256, 0, stream>>>(emb, pw, pb, Cpack, cn, z, Zpack, packed, counts);
    argmin_kernel<<<(K_CODE / BN) * (T_TOK / BM), 256, 0, stream>>>(Zpack, Cpack, cn, packed);
    zq_kernel<<<(T_TOK * D_DIM / 4) / 256, 256, 0, stream>>>(z, Cpack, packed, out, counts, lpart);
    scalars_kernel<<<1, 256, 0, stream>>>(counts, lpart, out);
}

// Round 13
// 373.791 us; speedup vs baseline: 1.1323x; 1.0224x over previous
//
#include <hip/hip_runtime.h>
#include <math.h>

#define T_TOK 32768
#define D_DIM 128
#define K_CODE 8192
#define BM 256              // tokens per block (argmin): 4 waves x 64
#define BN 64               // codes per block (argmin)

typedef unsigned long long ull;
typedef _Float16 v8h __attribute__((ext_vector_type(8)));
typedef _Float16 v4h __attribute__((ext_vector_type(4)));
typedef float v16f __attribute__((ext_vector_type(16)));

#define SCALE 4096.0f        // 2^12: pushes f16 split residuals into normal range
#define DESCALE (1.0f / 4096.0f)
#define ACC_SCALE (-0x1p-23f)   // s' = cn - 2*dot (zn dropped: token-constant)

// Cpack layout (bytes): [cb=code/64][ (s*2+mt)*8+kc ][lane64][j8 f16]
// Zpack layout (bytes): [tb=token/32][ s ][ kc ][lane64][j8 f16]

// ---------------- prep: proj (blocks 0..2047) + prep_z (2048..3071) ---------
// Fused: the two producers are independent; one dispatch runs them
// concurrently instead of serialized (R10-verified, −9us vs separate).
__global__ __launch_bounds__(256) void prep_kernel(const float* __restrict__ E,
                                                   const float* __restrict__ W,
                                                   const float* __restrict__ b,
                                                   char* __restrict__ Cpack,
                                                   float* __restrict__ cn,
                                                   const float* __restrict__ Z,
                                                   char* __restrict__ Zpack,
                                                   ull* __restrict__ packed,
                                                   int* __restrict__ counts) {
    int tid = threadIdx.x;
    int lane = tid & 63;
    if (blockIdx.x < 2048) {
        // ---- proj: codebook row -> f16 split packs + cn (1 wave / row) ----
        int r = blockIdx.x * 4 + (tid >> 6);
        int l = lane;
        const float4* E4 = (const float4*)(E + (size_t)r * D_DIM);
        const float4* WA = (const float4*)(W + (size_t)l * D_DIM);
        const float4* WB = (const float4*)(W + (size_t)(l + 64) * D_DIM);

        float4 aA = make_float4(0.f, 0.f, 0.f, 0.f);
        float4 aB = make_float4(0.f, 0.f, 0.f, 0.f);
#pragma unroll
        for (int dd = 0; dd < 32; ++dd) {
            float4 e = E4[dd];
            float4 wa = WA[dd], wb = WB[dd];
            aA.x = fmaf(e.x, wa.x, aA.x);
            aA.y = fmaf(e.y, wa.y, aA.y);
            aA.z = fmaf(e.z, wa.z, aA.z);
            aA.w = fmaf(e.w, wa.w, aA.w);
            aB.x = fmaf(e.x, wb.x, aB.x);
            aB.y = fmaf(e.y, wb.y, aB.y);
            aB.z = fmaf(e.z, wb.z, aB.z);
            aB.w = fmaf(e.w, wb.w, aB.w);
        }
        float vA = ((aA.x + aA.y) + (aA.z + aA.w)) + b[l];
        float vB = ((aB.x + aB.y) + (aB.z + aB.w)) + b[l + 64];

        char* cp = Cpack + (size_t)(r >> 6) * 32768;
        int mt = (r >> 5) & 1, rs = r & 31;
        {   // d = l
            int kc = l >> 4, hf = (l >> 3) & 1, j = l & 7;
            float f = vA * SCALE;
            _Float16 h = (_Float16)f;
            _Float16 m = (_Float16)(f - (float)h);
            size_t off = (size_t)((mt * 8 + kc) * 1024 + (hf * 32 + rs) * 16 + j * 2);
            *(_Float16*)(cp + off) = h;
            *(_Float16*)(cp + off + 16384) = m;
        }
        {   // d = l + 64
            int d = l + 64;
            int kc = d >> 4, hf = (d >> 3) & 1, j = d & 7;
            float f = vB * SCALE;
            _Float16 h = (_Float16)f;
            _Float16 m = (_Float16)(f - (float)h);
            size_t off = (size_t)((mt * 8 + kc) * 1024 + (hf * 32 + rs) * 16 + j * 2);
            *(_Float16*)(cp + off) = h;
            *(_Float16*)(cp + off + 16384) = m;
        }

        float s = vA * vA + vB * vB;
#pragma unroll
        for (int off = 32; off > 0; off >>= 1) s += __shfl_down(s, off, 64);
        if (l == 0) cn[r] = s;
    } else {
        // ---- prep_z: z -> f16 split packs + fused inits ----
        int tb = blockIdx.x - 2048;   // 32-token group
        int w = tid >> 6;

        int g = tb * 256 + tid;
        if (g < T_TOK) packed[g] = ~0ull;
        if (g < K_CODE) counts[g] = 0;

        char* zp = Zpack + (size_t)tb * 16384;
#pragma unroll
        for (int kq = 0; kq < 2; ++kq) {
            int kc = 2 * w + kq;
            const float* src = Z + (size_t)(tb * 32 + (lane & 31)) * D_DIM
                                 + kc * 16 + (lane >> 5) * 8;
            float4 a = *(const float4*)(src);
            float4 c = *(const float4*)(src + 4);
            float vals[8] = {a.x, a.y, a.z, a.w, c.x, c.y, c.z, c.w};
            v8h h, m;
#pragma unroll
            for (int j = 0; j < 8; ++j) {
                float f = vals[j] * SCALE;
                _Float16 hh = (_Float16)f;
                h[j] = hh;
                m[j] = (_Float16)(f - (float)hh);
            }
            *(v8h*)(zp + (size_t)(kc * 1024 + lane * 16)) = h;
            *(v8h*)(zp + (size_t)(8192 + kc * 1024 + lane * 16)) = m;
        }
    }
}

// ---------------- MFMA argmin: best-known config (R10 consolidation) --------
// Nine probes (occupancy x2, B-depth 3, A-dbuf, block shape, barriers,
// persistence x2, epilogue tree) all null or regress around the 206-208us
// equilibrium: L2 BW (B-refills ~61us + staging), LDS (~41us), VALU (~65us),
// matrix (~95us) sharing the machine. When the matrix pipe runs it is at
// ~95% of the f16 issue floor; R11 (no-LDS) proved staging is load-bearing;
// R12 proved the lean serial epilogue beats the encode-heavy tree. This is
// the measured-best configuration (366.8us total): fused prep + A double-
// buffer + 3-slot B prefetch + serial first-min epilogue + XCD swizzle.
__global__ __launch_bounds__(256, 3) void argmin_kernel(const char* __restrict__ Zpack,
                                                        const char* __restrict__ Cpack,
                                                        const float* __restrict__ cn,
                                                        ull* __restrict__ packed) {
    __shared__ __align__(16) char lds[33024];   // 32768 A-pack + 256 cn

    int tid = threadIdx.x;
    int lane = tid & 63;
    int w = tid >> 6;                  // 0..3
    int half_id = lane >> 5;

    // XCD swizzle: window in HIGH bits of q -> co-resident blocks share one
    // window (L2-hot Zpack); Cpack cycles L2-resident.
    int bid = blockIdx.x;
    int xcd = bid & 7;
    int q = bid >> 3;
    int cb = q & 127;                  // code block (64 codes)
    int win = xcd + 8 * (q >> 7);      // token window (256 tokens)
    int nb = cb * BN;
    int mb = win * BM;

    // ---- one-time stage: A-pack via async global_load_lds (16B, linear) ----
    {
        const char* src = Cpack + (size_t)cb * 32768;
#pragma unroll
        for (int it = 0; it < 8; ++it) {
            int off = it * 4096 + tid * 16;
            __builtin_amdgcn_global_load_lds(
                (const __attribute__((address_space(1))) void*)(src + off),
                (__attribute__((address_space(3))) void*)(lds + off),
                16, 0, 0);
        }
        if (tid < 64) ((float*)(lds + 32768))[tid] = cn[nb + tid];
    }

    int tbw = (mb >> 5) + 2 * w;       // wave w owns token groups 2w, 2w+1
    const char* zb0 = Zpack + (size_t)tbw * 16384 + lane * 16;

    // 3-slot register prefetch: pb[frag = n*2 + split][slot = kc%3]
    v8h pb[4][3];
#pragma unroll
    for (int n = 0; n < 2; ++n) {
        pb[2 * n + 0][0] = *(const v8h*)(zb0 + n * 16384);
        pb[2 * n + 1][0] = *(const v8h*)(zb0 + n * 16384 + 8192);
        pb[2 * n + 0][1] = *(const v8h*)(zb0 + n * 16384 + 1024);
        pb[2 * n + 1][1] = *(const v8h*)(zb0 + n * 16384 + 8192 + 1024);
    }

    __syncthreads();   // drains staging; LDS read-only after this

    const char* ab = lds + lane * 16;
    const float* cn_s = (const float*)(lds + 32768);

    v16f acc[2][2];               // [mt codes][n token-groups]
#pragma unroll
    for (int mt = 0; mt < 2; ++mt)
#pragma unroll
        for (int n = 0; n < 2; ++n) acc[mt][n] = (v16f)0.f;

    // A double-buffer: Af[kc&1][frag] -- prologue loads kc=0 (post-barrier)
    v8h Af[2][4];
#pragma unroll
    for (int f = 0; f < 4; ++f)
        Af[0][f] = *(const v8h*)(ab + (f * 8 + 0) * 1024);

#pragma unroll
    for (int kc = 0; kc < 8; ++kc) {
        int curb = kc % 3;
        int cura = kc & 1;

        // issue kc+1's A ds_reads FIRST (consumed after 12 MFMAs)
        if (kc < 7) {
#pragma unroll
            for (int f = 0; f < 4; ++f)
                Af[cura ^ 1][f] = *(const v8h*)(ab + (f * 8 + kc + 1) * 1024);
        }

        // deep B refill: slot (kc+2)%3 consumed at kc-1; data used at kc+2
        if (kc < 6) {
            int slot = (kc + 2) % 3;
#pragma unroll
            for (int n = 0; n < 2; ++n) {
                pb[2 * n + 0][slot] = *(const v8h*)(zb0 + n * 16384 + (kc + 2) * 1024);
                pb[2 * n + 1][slot] = *(const v8h*)(zb0 + n * 16384 + 8192 + (kc + 2) * 1024);
            }
        }

        __builtin_amdgcn_s_setprio(1);
        // pass h*h
#pragma unroll
        for (int n = 0; n < 2; ++n)
            acc[0][n] = __builtin_amdgcn_mfma_f32_32x32x16_f16(Af[cura][0], pb[2 * n][curb], acc[0][n], 0, 0, 0);
#pragma unroll
        for (int n = 0; n < 2; ++n)
            acc[1][n] = __builtin_amdgcn_mfma_f32_32x32x16_f16(Af[cura][1], pb[2 * n][curb], acc[1][n], 0, 0, 0);
        // pass h*m
#pragma unroll
        for (int n = 0; n < 2; ++n)
            acc[0][n] = __builtin_amdgcn_mfma_f32_32x32x16_f16(Af[cura][0], pb[2 * n + 1][curb], acc[0][n], 0, 0, 0);
#pragma unroll
        for (int n = 0; n < 2; ++n)
            acc[1][n] = __builtin_amdgcn_mfma_f32_32x32x16_f16(Af[cura][1], pb[2 * n + 1][curb], acc[1][n], 0, 0, 0);
        // pass m*h
#pragma unroll
        for (int n = 0; n < 2; ++n)
            acc[0][n] = __builtin_amdgcn_mfma_f32_32x32x16_f16(Af[cura][2], pb[2 * n][curb], acc[0][n], 0, 0, 0);
#pragma unroll
        for (int n = 0; n < 2; ++n)
            acc[1][n] = __builtin_amdgcn_mfma_f32_32x32x16_f16(Af[cura][3], pb[2 * n][curb], acc[1][n], 0, 0, 0);
        __builtin_amdgcn_s_setprio(0);
    }

    // ---- epilogue: in-lane argmin per token group (zn-free: s' = cn - 2dot,
    // token-constant zn cancels in every comparison) ----
    float best[2];
    int bi[2];
#pragma unroll
    for (int n = 0; n < 2; ++n) { best[n] = 3.4e38f; bi[n] = nb; }

#pragma unroll
    for (int mt = 0; mt < 2; ++mt) {
        float cnreg[16];
#pragma unroll
        for (int reg = 0; reg < 16; ++reg) {
            int mrow = 32 * mt + (reg & 3) + 8 * (reg >> 2) + 4 * half_id;
            cnreg[reg] = cn_s[mrow];
        }
#pragma unroll
        for (int n = 0; n < 2; ++n) {
#pragma unroll
            for (int reg = 0; reg < 16; ++reg) {
                // ascending code order within half -> strict < keeps first-min
                int mrow = 32 * mt + (reg & 3) + 8 * (reg >> 2) + 4 * half_id;
                int code = nb + mrow;
                float s = fmaf(acc[mt][n][reg], ACC_SCALE, cnreg[reg]);
                if (s < best[n]) { best[n] = s; bi[n] = code; }
            }
        }
    }

    // cross-half combine + XCD-local packed atomicMin
#pragma unroll
    for (int n = 0; n < 2; ++n) {
        float ob = __shfl_xor(best[n], 32, 64);
        int oi = __shfl_xor(bi[n], 32, 64);
        if (ob < best[n] || (ob == best[n] && oi < bi[n])) { best[n] = ob; bi[n] = oi; }
        if ((n & 1) == half_id) {
            int tok = mb + w * 64 + n * 32 + (lane & 31);
            // monotone total-order encode of f32 (s' may be negative):
            // >=0: u^0x80000000 ; <0: u^0xFFFFFFFF. Equal s' -> equal key ->
            // min picks smaller code in low bits (first-min ties preserved).
            unsigned ub = __float_as_uint(best[n]);
            unsigned key = ub ^ ((unsigned)(((int)ub) >> 31) | 0x80000000u);
            ull pk = ((ull)key << 32) | (unsigned)bi[n];
            atomicMin(&packed[tok], pk);
        }
    }
}

// ---------------- zq: unpack winner, reconstruct code row, out + counts + loss
__global__ __launch_bounds__(256) void zq_kernel(const float* __restrict__ Z,
                                                 const char* __restrict__ Cpack,
                                                 const ull* __restrict__ packed,
                                                 float* __restrict__ out,
                                                 int* __restrict__ counts,
                                                 float* __restrict__ lpart) {
    int gid = blockIdx.x * 256 + threadIdx.x;   // over T*D/4 float4s
    int t = gid >> 5;                           // 32 float4 per token
    int d4 = gid & 31;
    int idx = (int)(packed[t] & 0xFFFFFFFFull);
    if (d4 == 0) atomicAdd(&counts[idx], 1);

    // reconstruct c[d0..d0+3] = (ch + cm) * 2^-12 (exact sum: spans < 24 bits)
    int d0 = 4 * d4;
    int kc = d0 >> 4, hf = (d0 >> 3) & 1, j0 = d0 & 7;
    const char* cp = Cpack + (size_t)(idx >> 6) * 32768
                   + (size_t)((((idx >> 5) & 1) * 8 + kc) * 1024
                              + (hf * 32 + (idx & 31)) * 16 + j0 * 2);
    v4h h = *(const v4h*)(cp);
    v4h m = *(const v4h*)(cp + 16384);
    float4 cv;
    cv.x = ((float)h[0] + (float)m[0]) * DESCALE;
    cv.y = ((float)h[1] + (float)m[1]) * DESCALE;
    cv.z = ((float)h[2] + (float)m[2]) * DESCALE;
    cv.w = ((float)h[3] + (float)m[3]) * DESCALE;

    float4 zv = ((const float4*)Z)[gid];
    float dx = cv.x - zv.x, dy = cv.y - zv.y, dz = cv.z - zv.z, dw = cv.w - zv.w;
    float4 o;
    o.x = zv.x + dx;    // z + (z_q - z): match reference elementwise rounding
    o.y = zv.y + dy;
    o.z = zv.z + dz;
    o.w = zv.w + dw;
    ((float4*)out)[gid] = o;

    float ls = dx * dx + dy * dy + dz * dz + dw * dw;
#pragma unroll
    for (int off = 32; off > 0; off >>= 1) ls += __shfl_down(ls, off, 64);
    __shared__ float red[4];
    int lane = threadIdx.x & 63, w = threadIdx.x >> 6;
    if (lane == 0) red[w] = ls;
    __syncthreads();
    // per-block partial store: no same-address atomic serialization
    if (threadIdx.x == 0) lpart[blockIdx.x] = (red[0] + red[1]) + (red[2] + red[3]);
}

// ---------------- scalars: commit_loss (from partials), perplexity ----------
__global__ __launch_bounds__(256) void scalars_kernel(const int* __restrict__ counts,
                                                      const float* __restrict__ lpart,
                                                      float* __restrict__ out) {
    float s = 0.f;
    for (int i = threadIdx.x; i < K_CODE; i += 256) {
        float e = (float)counts[i] * (1.0f / (float)T_TOK);
        s += e * logf(e + 1e-8f);
    }
    float ls = 0.f;
    for (int i = threadIdx.x; i < 4096; i += 256) ls += lpart[i];
#pragma unroll
    for (int off = 32; off > 0; off >>= 1) {
        s += __shfl_down(s, off, 64);
        ls += __shfl_down(ls, off, 64);
    }
    __shared__ float red[8];
    int lane = threadIdx.x & 63, w = threadIdx.x >> 6;
    if (lane == 0) { red[w] = s; red[4 + w] = ls; }
    __syncthreads();
    if (threadIdx.x == 0) {
        float ssum = (red[0] + red[1]) + (red[2] + red[3]);
        float lsum = (red[4] + red[5]) + (red[6] + red[7]);
        out[(size_t)T_TOK * D_DIM + 0] = 1.25f * lsum / (float)((size_t)T_TOK * D_DIM);
        out[(size_t)T_TOK * D_DIM + 1] = expf(-ssum);
    }
}

extern "C" void kernel_launch(void* const* d_in, const int* in_sizes, int n_in,
                              void* d_out, int out_size, void* d_ws, size_t ws_size,
                              hipStream_t stream) {
    const float* z   = (const float*)d_in[0];   // [8,4096,128]
    const float* emb = (const float*)d_in[1];   // [8192,128]
    const float* pw  = (const float*)d_in[2];   // [128,128]
    const float* pb  = (const float*)d_in[3];   // [128]
    float* out = (float*)d_out;

    // Zpack (f16 split fragments, 16.78 MB) lives in d_out: dead scratch until
    // zq_kernel overwrites d_out with the final z_q_st.
    char* Zpack = (char*)d_out;

    char* ws = (char*)d_ws;
    // layout (bytes):
    //   Cpack:  0        .. 4194304   (128 cb x 32768)
    //   cn:     4194304  .. 4227072   (8192 f32)
    //   lpart:  4227072  .. 4243456   (4096 f32)
    //   packed: 4358144  .. 4620288   (32768 u64)
    //   counts: 4620288  .. 4653056   (8192 i32)
    char*  Cpack  = ws + 0;
    float* cn     = (float*)(ws + 4194304);
    float* lpart  = (float*)(ws + 4227072);
    ull*   packed = (ull*)  (ws + 4358144);
    int*   counts = (int*)  (ws + 4620288);

    prep_kernel<<<3072, 256, 0, stream>>>(emb, pw, pb, Cpack, cn, z, Zpack, packed, counts);
    argmin_kernel<<<(K_CODE / BN) * (T_TOK / BM), 256, 0, stream>>>(Zpack, Cpack, cn, packed);
    zq_kernel<<<(T_TOK * D_DIM / 4) / 256, 256, 0, stream>>>(z, Cpack, packed, out, counts, lpart);
    scalars_kernel<<<1, 256, 0, stream>>>(counts, lpart, out);
}